// Round 12
// baseline (193.956 us; speedup 1.0000x reference)
//
#include <hip/hip_runtime.h>
#include <hip/hip_bf16.h>

#define N_NODES 100000
#define IN_DIM 256
#define H_DIM 128
#define NEG_SLOPE 0.2f

#define NBUCK 782            // ceil(100000/128) buckets of 128 nodes
#define BKT_CAP 4096         // per-bucket tmp capacity (mean 2046, sigma ~45)
#define P1_EPT 16            // edges per thread in bin1 path (512 thr -> 8192 edges/block)

__device__ __forceinline__ float lrelu(float v) { return v > 0.f ? v : NEG_SLOPE * v; }
__device__ __forceinline__ float bflo(unsigned u) { return __uint_as_float(u << 16); }
__device__ __forceinline__ float bfhi(unsigned u) { return __uint_as_float(u & 0xffff0000u); }
__device__ __forceinline__ unsigned short f2bf(float f) {
    unsigned u = __float_as_uint(f);
    return (unsigned short)((u + 0x7fffu + ((u >> 16) & 1u)) >> 16);
}
__device__ __forceinline__ float rdlanef(float v, int j) {
    return __uint_as_float(__builtin_amdgcn_readlane(__float_as_uint(v), j));
}

typedef short bfrag __attribute__((ext_vector_type(8)));   // 8 bf16 (4 VGPRs)
typedef float f32x4 __attribute__((ext_vector_type(4)));

// ---- prep_w: W1 fp32 [k][col] -> bf16 col-major Wb[col][k] (64 KB, L2-resident) ----
__global__ __launch_bounds__(256) void prep_w(const float* __restrict__ W,
                                              unsigned short* __restrict__ Wb) {
    int idx = blockIdx.x * 1024 + threadIdx.x;
#pragma unroll
    for (int it = 0; it < 4; ++it, idx += 256) {
        int k = idx >> 7;
        int col = idx & 127;
        Wb[col * 256 + k] = f2bf(W[idx]);   // coalesced read, scattered 2B write (32K total)
    }
}

// ==== fused kernel: blocks [0,p1B) bin edges into 128-node buckets; blocks [p1B,..)
// ==== MFMA GEMM h=bf16(x@W1) + as1/ad1 dots. B-fragments read DIRECTLY from L2-hot
// ==== Wb (no LDS staging, no barrier) -> LDS only 32KB bounce -> ~4 blocks/CU.
__global__ __launch_bounds__(512) void fused_gemm_bin1(const float* __restrict__ x,
                                                       const unsigned short* __restrict__ Wb,
                                                       const float* __restrict__ a_src,
                                                       const float* __restrict__ a_dst,
                                                       unsigned short* __restrict__ hb,
                                                       float* __restrict__ as1,
                                                       float* __restrict__ ad1,
                                                       const int* __restrict__ src,
                                                       const int* __restrict__ dst,
                                                       int* __restrict__ bktAlloc,
                                                       unsigned* __restrict__ tmp,
                                                       int E, int p1B) {
    __shared__ __align__(16) char smemraw[32768];
    const int tid = threadIdx.x;

    if ((int)blockIdx.x < p1B) {
        // ---------- bin1: partition packed (dl<<17|src) into 128-node buckets ----------
        int* hist  = (int*)smemraw;          // 1024 (>= NBUCK)
        int* basev = hist + 1024;
        int* hist2 = basev + 1024;           // 3*4KB = 12KB
        hist[tid] = 0; hist[tid + 512] = 0;
        hist2[tid] = 0; hist2[tid + 512] = 0;
        __syncthreads();
        const int e0 = blockIdx.x * (512 * P1_EPT) + tid * P1_EPT;
        int sv[P1_EPT], dv[P1_EPT];
#pragma unroll
        for (int i = 0; i < P1_EPT; ++i) {
            int e = e0 + i;
            if (e < E) { sv[i] = src[e]; dv[i] = dst[e]; }
            else dv[i] = -1;
        }
#pragma unroll
        for (int i = 0; i < P1_EPT; ++i)
            if (dv[i] >= 0) atomicAdd(&hist[dv[i] >> 7], 1);
        __syncthreads();
        for (int t = tid; t < NBUCK; t += 512) {
            int c = hist[t];
            basev[t] = c ? atomicAdd(&bktAlloc[t], c) : 0;
        }
        __syncthreads();
#pragma unroll
        for (int i = 0; i < P1_EPT; ++i) {
            if (dv[i] >= 0) {
                int b = dv[i] >> 7;
                int r = atomicAdd(&hist2[b], 1);
                int pos = basev[b] + r;
                if (pos < BKT_CAP)
                    tmp[b * BKT_CAP + pos] =
                        ((unsigned)(dv[i] & 127) << 17) | (unsigned)sv[i];
            }
        }
        return;
    }

    // ---------- GEMM path: 128 rows/block, B direct from L2 ----------
    unsigned short* lds = (unsigned short*)smemraw;   // 32 KB D bounce only
    const int w = tid >> 6;          // wave 0..7
    const int lane = tid & 63;
    const int lo = lane & 15;
    const int hi = lane >> 4;        // 0..3
    const int row0 = ((int)blockIdx.x - p1B) * 128;

    int arow = row0 + w * 16 + lo;
    if (arow >= N_NODES) arow = N_NODES - 1;
    const float* xrow = x + (size_t)arow * IN_DIM + hi * 8;

    // 8 per-lane fragment pointers into Wb; (c,kc) fragment = wp[c] + kc*32 elements
    const unsigned short* wp[8];
#pragma unroll
    for (int c = 0; c < 8; ++c)
        wp[c] = Wb + (size_t)((c * 16 + lo) * 256 + hi * 8);

    f32x4 acc[8] = {};
#pragma unroll
    for (int kc = 0; kc < 8; ++kc) {
        float4 xa = *reinterpret_cast<const float4*>(xrow + kc * 32);
        float4 xb = *reinterpret_cast<const float4*>(xrow + kc * 32 + 4);
        bfrag a;
        a[0] = (short)f2bf(xa.x); a[1] = (short)f2bf(xa.y);
        a[2] = (short)f2bf(xa.z); a[3] = (short)f2bf(xa.w);
        a[4] = (short)f2bf(xb.x); a[5] = (short)f2bf(xb.y);
        a[6] = (short)f2bf(xb.z); a[7] = (short)f2bf(xb.w);
#pragma unroll
        for (int c = 0; c < 8; ++c) {
            const bfrag b = *reinterpret_cast<const bfrag*>(wp[c] + kc * 32);
            acc[c] = __builtin_amdgcn_mfma_f32_16x16x32_bf16(a, b, acc[c], 0, 0, 0);
        }
    }

    // fused attention dots (fp32-exact)
    float asv[8], adv[8];
#pragma unroll
    for (int c = 0; c < 8; ++c) { asv[c] = a_src[c * 16 + lo]; adv[c] = a_dst[c * 16 + lo]; }
#pragma unroll
    for (int q = 0; q < 4; ++q) {
        float ps = 0.f, pd = 0.f;
#pragma unroll
        for (int c = 0; c < 8; ++c) { ps += acc[c][q] * asv[c]; pd += acc[c][q] * adv[c]; }
#pragma unroll
        for (int off = 8; off; off >>= 1) {
            ps += __shfl_xor(ps, off);
            pd += __shfl_xor(pd, off);
        }
        int grow = row0 + w * 16 + hi * 4 + q;
        if (lo == 0 && grow < N_NODES) { as1[grow] = ps; ad1[grow] = pd; }
    }

    // bounce D through LDS (128x128 bf16 = 32KB) for coalesced bf16 stores
    __syncthreads();
#pragma unroll
    for (int c = 0; c < 8; ++c)
#pragma unroll
        for (int q = 0; q < 4; ++q)
            lds[(w * 16 + hi * 4 + q) * 128 + c * 16 + lo] = f2bf(acc[c][q]);
    __syncthreads();
#pragma unroll
    for (int i = 0; i < 4; ++i) {
        int idx = i * 512 + tid;
        int row = idx >> 4;
        int chunk = idx & 15;
        int grow = row0 + row;
        if (grow < N_NODES) {
            uint4 v = *reinterpret_cast<const uint4*>(&lds[row * 128 + chunk * 8]);
            *reinterpret_cast<uint4*>(&hb[(size_t)grow * H_DIM + chunk * 8]) = v;
        }
    }
}

// ---- bin2: per-bucket -> rowptr (global base via in-block 782-scan) + sorted col ----
__global__ __launch_bounds__(1024) void bin_pass2(const unsigned* __restrict__ tmp,
                                                  const int* __restrict__ bktAlloc,
                                                  int* __restrict__ rowptr,
                                                  int* __restrict__ col) {
    __shared__ int bscan[1024];
    __shared__ int cnt[128], sc[128], rp[128];
    __shared__ int s_ebeg;
    const int b = blockIdx.x;
    const int nb0 = b << 7;
    const int nmax = min(128, N_NODES - nb0);
    const int tid = threadIdx.x;

    // exclusive scan of the 782 bucket counts -> this bucket's global edge base
    int v = (tid < NBUCK) ? min(bktAlloc[tid], BKT_CAP) : 0;
    bscan[tid] = v;
    __syncthreads();
    for (int off = 1; off < 1024; off <<= 1) {
        int u = (tid >= off) ? bscan[tid - off] : 0;
        __syncthreads();
        bscan[tid] += u;
        __syncthreads();
    }
    const int myCnt = min(bktAlloc[b], BKT_CAP);
    if (tid == 0) s_ebeg = bscan[b] - myCnt;
    if (tid < 128) cnt[tid] = 0;
    __syncthreads();
    const int ebeg = s_ebeg;
    const unsigned* btmp = tmp + (size_t)b * BKT_CAP;

    // pass A: per-node histogram within bucket
    for (int i = tid; i < myCnt; i += 1024)
        atomicAdd(&cnt[btmp[i] >> 17], 1);
    __syncthreads();
    if (tid < 128) sc[tid] = cnt[tid];
    __syncthreads();
    for (int off = 1; off < 128; off <<= 1) {
        int u = (tid < 128 && tid >= off) ? sc[tid - off] : 0;
        __syncthreads();
        if (tid < 128) sc[tid] += u;
        __syncthreads();
    }
    if (tid < 128) { rp[tid] = ebeg + sc[tid] - cnt[tid]; cnt[tid] = 0; }
    __syncthreads();
    if (tid < nmax) rowptr[nb0 + tid] = rp[tid];
    if (b == NBUCK - 1 && tid == 0) rowptr[N_NODES] = ebeg + myCnt;
    // pass B: scatter into per-node-sorted col
    for (int i = tid; i < myCnt; i += 1024) {
        unsigned e = btmp[i];
        int s = (int)(e & 0x1FFFFu);
        int dl = (int)(e >> 17);
        int off = atomicAdd(&cnt[dl], 1);
        col[rp[dl] + off] = s;
    }
}

// ------- Layer-1 aggregate (R8 known-good): 25000 blocks, wave per node -------
__global__ __launch_bounds__(256) void agg1_kernel(const unsigned int* __restrict__ hbu,
                                                   const float* __restrict__ as1,
                                                   const float* __restrict__ ad1,
                                                   const int* __restrict__ rowptr,
                                                   const int* __restrict__ col,
                                                   const float* __restrict__ b1,
                                                   const float* __restrict__ W2,
                                                   const float* __restrict__ a2s,
                                                   const float* __restrict__ a2d,
                                                   float* __restrict__ h2,
                                                   float* __restrict__ as2,
                                                   float* __restrict__ ad2) {
    int node = blockIdx.x * 4 + (threadIdx.x >> 6);
    int lane = threadIdx.x & 63;
    if (node >= N_NODES) return;

    float adi = ad1[node];
    float wself = __expf(lrelu(as1[node] + adi));     // self loop weight
    unsigned hvs = hbu[(unsigned)node * 64u + lane];
    float ax = wself * bflo(hvs), ay = wself * bfhi(hvs);
    float lsum = 0.0f;

    const int beg = rowptr[node], end = rowptr[node + 1];
    for (int p0 = beg; p0 < end; p0 += 64) {
        const int jn = min(64, end - p0);
        int idx = p0 + (lane < jn ? lane : 0);
        int s_l = col[idx];                            // coalesced chunk read
        float e_l = (lane < jn) ? __expf(lrelu(as1[s_l] + adi)) : 0.0f;
        lsum += e_l;
        int j = 0;
        for (; j + 8 <= jn; j += 8) {
            const unsigned* r0 = hbu + ((size_t)__builtin_amdgcn_readlane(s_l, j)     << 6);
            const unsigned* r1 = hbu + ((size_t)__builtin_amdgcn_readlane(s_l, j + 1) << 6);
            const unsigned* r2 = hbu + ((size_t)__builtin_amdgcn_readlane(s_l, j + 2) << 6);
            const unsigned* r3 = hbu + ((size_t)__builtin_amdgcn_readlane(s_l, j + 3) << 6);
            const unsigned* r4 = hbu + ((size_t)__builtin_amdgcn_readlane(s_l, j + 4) << 6);
            const unsigned* r5 = hbu + ((size_t)__builtin_amdgcn_readlane(s_l, j + 5) << 6);
            const unsigned* r6 = hbu + ((size_t)__builtin_amdgcn_readlane(s_l, j + 6) << 6);
            const unsigned* r7 = hbu + ((size_t)__builtin_amdgcn_readlane(s_l, j + 7) << 6);
            unsigned v0 = r0[lane];
            unsigned v1 = r1[lane];
            unsigned v2 = r2[lane];
            unsigned v3 = r3[lane];
            unsigned v4 = r4[lane];
            unsigned v5 = r5[lane];
            unsigned v6 = r6[lane];
            unsigned v7 = r7[lane];
            float w0 = rdlanef(e_l, j);
            float w1 = rdlanef(e_l, j + 1);
            float w2 = rdlanef(e_l, j + 2);
            float w3 = rdlanef(e_l, j + 3);
            float w4 = rdlanef(e_l, j + 4);
            float w5 = rdlanef(e_l, j + 5);
            float w6 = rdlanef(e_l, j + 6);
            float w7 = rdlanef(e_l, j + 7);
            ax += (w0 * bflo(v0) + w1 * bflo(v1)) + (w2 * bflo(v2) + w3 * bflo(v3))
                + (w4 * bflo(v4) + w5 * bflo(v5)) + (w6 * bflo(v6) + w7 * bflo(v7));
            ay += (w0 * bfhi(v0) + w1 * bfhi(v1)) + (w2 * bfhi(v2) + w3 * bfhi(v3))
                + (w4 * bfhi(v4) + w5 * bfhi(v5)) + (w6 * bfhi(v6) + w7 * bfhi(v7));
        }
        for (; j < jn; ++j) {
            const unsigned* r = hbu + ((size_t)__builtin_amdgcn_readlane(s_l, j) << 6);
            float w = rdlanef(e_l, j);
            unsigned v = r[lane];
            ax += w * bflo(v);
            ay += w * bfhi(v);
        }
    }
#pragma unroll
    for (int off = 32; off; off >>= 1) lsum += __shfl_xor(lsum, off);
    float inv = 1.0f / (lsum + wself);

    float2 bb = *reinterpret_cast<const float2*>(&b1[lane * 2]);
    float o0 = fmaxf(ax * inv + bb.x, 0.0f);
    float o1 = fmaxf(ay * inv + bb.y, 0.0f);

    float4 w2 = *reinterpret_cast<const float4*>(&W2[lane * 4]);
    float p0 = o0 * w2.x + o1 * w2.z;
    float p1 = o0 * w2.y + o1 * w2.w;
#pragma unroll
    for (int off = 32; off; off >>= 1) {
        p0 += __shfl_xor(p0, off);
        p1 += __shfl_xor(p1, off);
    }
    if (lane == 0) {
        h2[node * 2 + 0] = p0;
        h2[node * 2 + 1] = p1;
        as2[node] = p0 * a2s[0] + p1 * a2s[1];
        ad2[node] = p0 * a2d[0] + p1 * a2d[1];
    }
}

// ---------------- Layer-2 aggregate: thread per node, no-max softmax ----------------
__global__ __launch_bounds__(256) void agg2_kernel(const float* __restrict__ h2,
                                                   const float* __restrict__ as2,
                                                   const float* __restrict__ ad2,
                                                   const int* __restrict__ rowptr,
                                                   const int* __restrict__ col,
                                                   const float* __restrict__ b2,
                                                   float* __restrict__ out) {
    int node = blockIdx.x * 256 + threadIdx.x;
    if (node >= N_NODES) return;
    const float2* __restrict__ h2v = (const float2*)h2;
    float adi = ad2[node];
    float w0s = __expf(lrelu(as2[node] + adi));
    float l = w0s;
    float2 hv0 = h2v[(unsigned)node];
    float a0 = w0s * hv0.x, a1 = w0s * hv0.y;
    int p = rowptr[node], end = rowptr[node + 1];
    for (; p + 4 <= end; p += 4) {
        unsigned s0 = (unsigned)col[p],     s1 = (unsigned)col[p + 1];
        unsigned s2 = (unsigned)col[p + 2], s3 = (unsigned)col[p + 3];
        float w0 = __expf(lrelu(as2[s0] + adi));
        float w1 = __expf(lrelu(as2[s1] + adi));
        float w2 = __expf(lrelu(as2[s2] + adi));
        float w3 = __expf(lrelu(as2[s3] + adi));
        float2 v0 = h2v[s0];
        float2 v1 = h2v[s1];
        float2 v2 = h2v[s2];
        float2 v3 = h2v[s3];
        l += (w0 + w1) + (w2 + w3);
        a0 += (w0 * v0.x + w1 * v1.x) + (w2 * v2.x + w3 * v3.x);
        a1 += (w0 * v0.y + w1 * v1.y) + (w2 * v2.y + w3 * v3.y);
    }
    for (; p < end; ++p) {
        unsigned s = (unsigned)col[p];
        float w = __expf(lrelu(as2[s] + adi));
        float2 hv = h2v[s];
        l += w;
        a0 += w * hv.x;
        a1 += w * hv.y;
    }
    float inv = 1.0f / l;
    out[node * 2 + 0] = a0 * inv + b2[0];
    out[node * 2 + 1] = a1 * inv + b2[1];
}

// ---------------- launch ----------------
static inline char* ws_bump(char*& p, size_t bytes) {
    char* r = p;
    p += (bytes + 255) & ~(size_t)255;
    return r;
}

extern "C" void kernel_launch(void* const* d_in, const int* in_sizes, int n_in,
                              void* d_out, int out_size, void* d_ws, size_t ws_size,
                              hipStream_t stream) {
    const float* x   = (const float*)d_in[0];
    const int*   ei  = (const int*)d_in[1];
    const float* W1  = (const float*)d_in[2];
    const float* a1s = (const float*)d_in[3];
    const float* a1d = (const float*)d_in[4];
    const float* b1  = (const float*)d_in[5];
    const float* W2  = (const float*)d_in[6];
    const float* a2s = (const float*)d_in[7];
    const float* a2d = (const float*)d_in[8];
    const float* b2  = (const float*)d_in[9];
    float* out = (float*)d_out;

    const int E = in_sizes[1] / 2;
    const int* src = ei;        // edge_index[0]
    const int* dstp = ei + E;   // edge_index[1]

    char* p = (char*)d_ws;
    unsigned short* hb = (unsigned short*)ws_bump(p, (size_t)N_NODES * H_DIM * 2);   // 25.6 MB
    unsigned* tmp  = (unsigned*)ws_bump(p, (size_t)NBUCK * BKT_CAP * 4);             // 12.8 MB
    unsigned short* Wb = (unsigned short*)ws_bump(p, (size_t)IN_DIM * H_DIM * 2);    // 64 KB
    float* as1    = (float*)ws_bump(p, (size_t)N_NODES * 4);
    float* ad1    = (float*)ws_bump(p, (size_t)N_NODES * 4);
    int*   rowptr = (int*)  ws_bump(p, (size_t)(N_NODES + 1) * 4);
    int*   col    = (int*)  ws_bump(p, (size_t)E * 4);
    int*   bktAlloc = (int*)ws_bump(p, 1024 * 4);
    float* h2     = (float*)ws_bump(p, (size_t)N_NODES * 2 * 4);
    float* as2    = (float*)ws_bump(p, (size_t)N_NODES * 4);
    float* ad2    = (float*)ws_bump(p, (size_t)N_NODES * 4);

    const int nodeBlocks = (N_NODES + 255) / 256;                 // 391
    const int p1Blocks = (E + 512 * P1_EPT - 1) / (512 * P1_EPT); // 196
    const int gemmBlocks = (N_NODES + 127) / 128;                 // 782

    hipMemsetAsync(bktAlloc, 0, 1024 * 4, stream);
    prep_w<<<32, 256, 0, stream>>>(W1, Wb);

    fused_gemm_bin1<<<p1Blocks + gemmBlocks, 512, 0, stream>>>(
        x, Wb, a1s, a1d, hb, as1, ad1, src, dstp, bktAlloc, tmp, E, p1Blocks);
    bin_pass2<<<NBUCK, 1024, 0, stream>>>(tmp, bktAlloc, rowptr, col);

    agg1_kernel<<<(N_NODES + 3) / 4, 256, 0, stream>>>((const unsigned int*)hb, as1, ad1,
                                                       rowptr, col, b1, W2, a2s, a2d,
                                                       h2, as2, ad2);
    agg2_kernel<<<nodeBlocks, 256, 0, stream>>>(h2, as2, ad2, rowptr, col, b2, out);
}

// Round 13
// 156.442 us; speedup vs baseline: 1.2398x; 1.2398x over previous
//
#include <hip/hip_runtime.h>
#include <hip/hip_bf16.h>

#define N_NODES 100000
#define IN_DIM 256
#define H_DIM 128
#define NEG_SLOPE 0.2f

#define NBUCK 782            // ceil(100000/128) buckets of 128 nodes
#define BKT_CAP 4096         // per-bucket tmp capacity (mean 2046, sigma ~45)
#define P1_EPT 16            // edges per thread in bin1 path (512 thr -> 8192 edges/block)

__device__ __forceinline__ float lrelu(float v) { return v > 0.f ? v : NEG_SLOPE * v; }
__device__ __forceinline__ float bflo(unsigned u) { return __uint_as_float(u << 16); }
__device__ __forceinline__ float bfhi(unsigned u) { return __uint_as_float(u & 0xffff0000u); }
__device__ __forceinline__ unsigned short f2bf(float f) {
    unsigned u = __float_as_uint(f);
    return (unsigned short)((u + 0x7fffu + ((u >> 16) & 1u)) >> 16);
}
__device__ __forceinline__ float rdlanef(float v, int j) {
    return __uint_as_float(__builtin_amdgcn_readlane(__float_as_uint(v), j));
}

typedef short bfrag __attribute__((ext_vector_type(8)));   // 8 bf16 (4 VGPRs)
typedef float f32x4 __attribute__((ext_vector_type(4)));

// ---- prep_w: W1 fp32 [k][col] -> Wb bf16 PRE-SWIZZLED phase-split [p][col][k'] ----
// Layout matches the GEMM's LDS image exactly: phase p holds k in [p*128,(p+1)*128);
// within a phase: addr = col*128 + (kbs<<3) + (k&7), kbs = (kb&8)|((kb&7)^(col&7)),
// kb = (k&127)>>3.  GEMM then stages each 32KB phase with a LINEAR copy.
__global__ __launch_bounds__(256) void prep_w(const float* __restrict__ W,
                                              unsigned short* __restrict__ Wb) {
    int idx = blockIdx.x * 1024 + threadIdx.x;
#pragma unroll
    for (int it = 0; it < 4; ++it, idx += 256) {
        int k = idx >> 7;            // 0..255
        int col = idx & 127;
        int p = k >> 7;
        int kb = (k & 127) >> 3;     // 0..15
        int rem = k & 7;
        int kbs = (kb & 8) | ((kb & 7) ^ (col & 7));
        Wb[p * 16384 + col * 128 + (kbs << 3) + rem] = f2bf(W[k * H_DIM + col]);
    }
}

// ==== fused kernel: blocks [0,p1B) bin edges into 128-node buckets; blocks [p1B,..)
// ==== MFMA GEMM h=bf16(x@W1)+dots. W staged from pre-swizzled Wb via linear copy,
// ==== two 32KB K-phases -> LDS 32KB -> 4 blocks/CU.
__global__ __launch_bounds__(512) void fused_gemm_bin1(const float* __restrict__ x,
                                                       const unsigned short* __restrict__ Wb,
                                                       const float* __restrict__ a_src,
                                                       const float* __restrict__ a_dst,
                                                       unsigned short* __restrict__ hb,
                                                       float* __restrict__ as1,
                                                       float* __restrict__ ad1,
                                                       const int* __restrict__ src,
                                                       const int* __restrict__ dst,
                                                       int* __restrict__ bktAlloc,
                                                       unsigned* __restrict__ tmp,
                                                       int E, int p1B) {
    __shared__ __align__(16) char smemraw[32768];
    const int tid = threadIdx.x;

    if ((int)blockIdx.x < p1B) {
        // ---------- bin1: partition packed (dl<<17|src) into 128-node buckets ----------
        int* hist  = (int*)smemraw;          // 1024 (>= NBUCK)
        int* basev = hist + 1024;
        int* hist2 = basev + 1024;           // 3*4KB = 12KB
        hist[tid] = 0; hist[tid + 512] = 0;
        hist2[tid] = 0; hist2[tid + 512] = 0;
        __syncthreads();
        const int e0 = blockIdx.x * (512 * P1_EPT) + tid * P1_EPT;
        int sv[P1_EPT], dv[P1_EPT];
#pragma unroll
        for (int i = 0; i < P1_EPT; ++i) {
            int e = e0 + i;
            if (e < E) { sv[i] = src[e]; dv[i] = dst[e]; }
            else dv[i] = -1;
        }
#pragma unroll
        for (int i = 0; i < P1_EPT; ++i)
            if (dv[i] >= 0) atomicAdd(&hist[dv[i] >> 7], 1);
        __syncthreads();
        for (int t = tid; t < NBUCK; t += 512) {
            int c = hist[t];
            basev[t] = c ? atomicAdd(&bktAlloc[t], c) : 0;
        }
        __syncthreads();
#pragma unroll
        for (int i = 0; i < P1_EPT; ++i) {
            if (dv[i] >= 0) {
                int b = dv[i] >> 7;
                int r = atomicAdd(&hist2[b], 1);
                int pos = basev[b] + r;
                if (pos < BKT_CAP)
                    tmp[b * BKT_CAP + pos] =
                        ((unsigned)(dv[i] & 127) << 17) | (unsigned)sv[i];
            }
        }
        return;
    }

    // ---------- GEMM path: 128 rows/block, two 32KB W phases ----------
    unsigned short* lds = (unsigned short*)smemraw;   // 32 KB: W phase, then D bounce
    const int w = tid >> 6;          // wave 0..7
    const int lane = tid & 63;
    const int lo = lane & 15;
    const int hi = lane >> 4;        // 0..3
    const int row0 = ((int)blockIdx.x - p1B) * 128;

    int arow = row0 + w * 16 + lo;
    if (arow >= N_NODES) arow = N_NODES - 1;
    const float* xrow = x + (size_t)arow * IN_DIM + hi * 8;

    f32x4 acc[8] = {};
#pragma unroll
    for (int ph = 0; ph < 2; ++ph) {
        __syncthreads();   // previous phase fully consumed (no-op cost at ph=0)
        {
            const uint4* wsrc = reinterpret_cast<const uint4*>(Wb + ph * 16384);
            uint4* wdst = reinterpret_cast<uint4*>(lds);
#pragma unroll
            for (int it = 0; it < 4; ++it)
                wdst[it * 512 + tid] = wsrc[it * 512 + tid];   // linear 32KB copy
        }
        __syncthreads();
#pragma unroll
        for (int kc2 = 0; kc2 < 4; ++kc2) {
            const int kc = ph * 4 + kc2;
            float4 xa = *reinterpret_cast<const float4*>(xrow + kc * 32);
            float4 xb = *reinterpret_cast<const float4*>(xrow + kc * 32 + 4);
            bfrag a;
            a[0] = (short)f2bf(xa.x); a[1] = (short)f2bf(xa.y);
            a[2] = (short)f2bf(xa.z); a[3] = (short)f2bf(xa.w);
            a[4] = (short)f2bf(xb.x); a[5] = (short)f2bf(xb.y);
            a[6] = (short)f2bf(xb.z); a[7] = (short)f2bf(xb.w);
            int kbh = kc2 * 4 + hi;                 // 0..15 (phase-local k-block)
#pragma unroll
            for (int c = 0; c < 8; ++c) {
                int col = c * 16 + lo;
                int kbs = (kbh & 8) | ((kbh & 7) ^ (col & 7));
                const bfrag b = *reinterpret_cast<const bfrag*>(
                    &lds[col * 128 + (kbs << 3)]);
                acc[c] = __builtin_amdgcn_mfma_f32_16x16x32_bf16(a, b, acc[c], 0, 0, 0);
            }
        }
    }

    // fused attention dots (fp32-exact)
    float asv[8], adv[8];
#pragma unroll
    for (int c = 0; c < 8; ++c) { asv[c] = a_src[c * 16 + lo]; adv[c] = a_dst[c * 16 + lo]; }
#pragma unroll
    for (int q = 0; q < 4; ++q) {
        float ps = 0.f, pd = 0.f;
#pragma unroll
        for (int c = 0; c < 8; ++c) { ps += acc[c][q] * asv[c]; pd += acc[c][q] * adv[c]; }
#pragma unroll
        for (int off = 8; off; off >>= 1) {
            ps += __shfl_xor(ps, off);
            pd += __shfl_xor(pd, off);
        }
        int grow = row0 + w * 16 + hi * 4 + q;
        if (lo == 0 && grow < N_NODES) { as1[grow] = ps; ad1[grow] = pd; }
    }

    // bounce D through LDS (128x128 bf16 = 32KB) for coalesced bf16 stores
    __syncthreads();
#pragma unroll
    for (int c = 0; c < 8; ++c)
#pragma unroll
        for (int q = 0; q < 4; ++q)
            lds[(w * 16 + hi * 4 + q) * 128 + c * 16 + lo] = f2bf(acc[c][q]);
    __syncthreads();
#pragma unroll
    for (int i = 0; i < 4; ++i) {
        int idx = i * 512 + tid;
        int row = idx >> 4;
        int chunk = idx & 15;
        int grow = row0 + row;
        if (grow < N_NODES) {
            uint4 v = *reinterpret_cast<const uint4*>(&lds[row * 128 + chunk * 8]);
            *reinterpret_cast<uint4*>(&hb[(size_t)grow * H_DIM + chunk * 8]) = v;
        }
    }
}

// ---- bin2: per-bucket -> rowptr (global base via in-block 782-scan) + sorted col ----
__global__ __launch_bounds__(1024) void bin_pass2(const unsigned* __restrict__ tmp,
                                                  const int* __restrict__ bktAlloc,
                                                  int* __restrict__ rowptr,
                                                  int* __restrict__ col) {
    __shared__ int bscan[1024];
    __shared__ int cnt[128], sc[128], rp[128];
    __shared__ int s_ebeg;
    const int b = blockIdx.x;
    const int nb0 = b << 7;
    const int nmax = min(128, N_NODES - nb0);
    const int tid = threadIdx.x;

    int v = (tid < NBUCK) ? min(bktAlloc[tid], BKT_CAP) : 0;
    bscan[tid] = v;
    __syncthreads();
    for (int off = 1; off < 1024; off <<= 1) {
        int u = (tid >= off) ? bscan[tid - off] : 0;
        __syncthreads();
        bscan[tid] += u;
        __syncthreads();
    }
    const int myCnt = min(bktAlloc[b], BKT_CAP);
    if (tid == 0) s_ebeg = bscan[b] - myCnt;
    if (tid < 128) cnt[tid] = 0;
    __syncthreads();
    const int ebeg = s_ebeg;
    const unsigned* btmp = tmp + (size_t)b * BKT_CAP;

    for (int i = tid; i < myCnt; i += 1024)
        atomicAdd(&cnt[btmp[i] >> 17], 1);
    __syncthreads();
    if (tid < 128) sc[tid] = cnt[tid];
    __syncthreads();
    for (int off = 1; off < 128; off <<= 1) {
        int u = (tid < 128 && tid >= off) ? sc[tid - off] : 0;
        __syncthreads();
        if (tid < 128) sc[tid] += u;
        __syncthreads();
    }
    if (tid < 128) { rp[tid] = ebeg + sc[tid] - cnt[tid]; cnt[tid] = 0; }
    __syncthreads();
    if (tid < nmax) rowptr[nb0 + tid] = rp[tid];
    if (b == NBUCK - 1 && tid == 0) rowptr[N_NODES] = ebeg + myCnt;
    for (int i = tid; i < myCnt; i += 1024) {
        unsigned e = btmp[i];
        int s = (int)(e & 0x1FFFFu);
        int dl = (int)(e >> 17);
        int off = atomicAdd(&cnt[dl], 1);
        col[rp[dl] + off] = s;
    }
}

// ------- Layer-1 aggregate (R8 known-good): 25000 blocks, wave per node -------
__global__ __launch_bounds__(256) void agg1_kernel(const unsigned int* __restrict__ hbu,
                                                   const float* __restrict__ as1,
                                                   const float* __restrict__ ad1,
                                                   const int* __restrict__ rowptr,
                                                   const int* __restrict__ col,
                                                   const float* __restrict__ b1,
                                                   const float* __restrict__ W2,
                                                   const float* __restrict__ a2s,
                                                   const float* __restrict__ a2d,
                                                   float* __restrict__ h2,
                                                   float* __restrict__ as2,
                                                   float* __restrict__ ad2) {
    int node = blockIdx.x * 4 + (threadIdx.x >> 6);
    int lane = threadIdx.x & 63;
    if (node >= N_NODES) return;

    float adi = ad1[node];
    float wself = __expf(lrelu(as1[node] + adi));     // self loop weight
    unsigned hvs = hbu[(unsigned)node * 64u + lane];
    float ax = wself * bflo(hvs), ay = wself * bfhi(hvs);
    float lsum = 0.0f;

    const int beg = rowptr[node], end = rowptr[node + 1];
    for (int p0 = beg; p0 < end; p0 += 64) {
        const int jn = min(64, end - p0);
        int idx = p0 + (lane < jn ? lane : 0);
        int s_l = col[idx];                            // coalesced chunk read
        float e_l = (lane < jn) ? __expf(lrelu(as1[s_l] + adi)) : 0.0f;
        lsum += e_l;
        int j = 0;
        for (; j + 8 <= jn; j += 8) {
            const unsigned* r0 = hbu + ((size_t)__builtin_amdgcn_readlane(s_l, j)     << 6);
            const unsigned* r1 = hbu + ((size_t)__builtin_amdgcn_readlane(s_l, j + 1) << 6);
            const unsigned* r2 = hbu + ((size_t)__builtin_amdgcn_readlane(s_l, j + 2) << 6);
            const unsigned* r3 = hbu + ((size_t)__builtin_amdgcn_readlane(s_l, j + 3) << 6);
            const unsigned* r4 = hbu + ((size_t)__builtin_amdgcn_readlane(s_l, j + 4) << 6);
            const unsigned* r5 = hbu + ((size_t)__builtin_amdgcn_readlane(s_l, j + 5) << 6);
            const unsigned* r6 = hbu + ((size_t)__builtin_amdgcn_readlane(s_l, j + 6) << 6);
            const unsigned* r7 = hbu + ((size_t)__builtin_amdgcn_readlane(s_l, j + 7) << 6);
            unsigned v0 = r0[lane];
            unsigned v1 = r1[lane];
            unsigned v2 = r2[lane];
            unsigned v3 = r3[lane];
            unsigned v4 = r4[lane];
            unsigned v5 = r5[lane];
            unsigned v6 = r6[lane];
            unsigned v7 = r7[lane];
            float w0 = rdlanef(e_l, j);
            float w1 = rdlanef(e_l, j + 1);
            float w2 = rdlanef(e_l, j + 2);
            float w3 = rdlanef(e_l, j + 3);
            float w4 = rdlanef(e_l, j + 4);
            float w5 = rdlanef(e_l, j + 5);
            float w6 = rdlanef(e_l, j + 6);
            float w7 = rdlanef(e_l, j + 7);
            ax += (w0 * bflo(v0) + w1 * bflo(v1)) + (w2 * bflo(v2) + w3 * bflo(v3))
                + (w4 * bflo(v4) + w5 * bflo(v5)) + (w6 * bflo(v6) + w7 * bflo(v7));
            ay += (w0 * bfhi(v0) + w1 * bfhi(v1)) + (w2 * bfhi(v2) + w3 * bfhi(v3))
                + (w4 * bfhi(v4) + w5 * bfhi(v5)) + (w6 * bfhi(v6) + w7 * bfhi(v7));
        }
        for (; j < jn; ++j) {
            const unsigned* r = hbu + ((size_t)__builtin_amdgcn_readlane(s_l, j) << 6);
            float w = rdlanef(e_l, j);
            unsigned v = r[lane];
            ax += w * bflo(v);
            ay += w * bfhi(v);
        }
    }
#pragma unroll
    for (int off = 32; off; off >>= 1) lsum += __shfl_xor(lsum, off);
    float inv = 1.0f / (lsum + wself);

    float2 bb = *reinterpret_cast<const float2*>(&b1[lane * 2]);
    float o0 = fmaxf(ax * inv + bb.x, 0.0f);
    float o1 = fmaxf(ay * inv + bb.y, 0.0f);

    float4 w2 = *reinterpret_cast<const float4*>(&W2[lane * 4]);
    float p0 = o0 * w2.x + o1 * w2.z;
    float p1 = o0 * w2.y + o1 * w2.w;
#pragma unroll
    for (int off = 32; off; off >>= 1) {
        p0 += __shfl_xor(p0, off);
        p1 += __shfl_xor(p1, off);
    }
    if (lane == 0) {
        h2[node * 2 + 0] = p0;
        h2[node * 2 + 1] = p1;
        as2[node] = p0 * a2s[0] + p1 * a2s[1];
        ad2[node] = p0 * a2d[0] + p1 * a2d[1];
    }
}

// ---------------- Layer-2 aggregate: thread per node, no-max softmax ----------------
__global__ __launch_bounds__(256) void agg2_kernel(const float* __restrict__ h2,
                                                   const float* __restrict__ as2,
                                                   const float* __restrict__ ad2,
                                                   const int* __restrict__ rowptr,
                                                   const int* __restrict__ col,
                                                   const float* __restrict__ b2,
                                                   float* __restrict__ out) {
    int node = blockIdx.x * 256 + threadIdx.x;
    if (node >= N_NODES) return;
    const float2* __restrict__ h2v = (const float2*)h2;
    float adi = ad2[node];
    float w0s = __expf(lrelu(as2[node] + adi));
    float l = w0s;
    float2 hv0 = h2v[(unsigned)node];
    float a0 = w0s * hv0.x, a1 = w0s * hv0.y;
    int p = rowptr[node], end = rowptr[node + 1];
    for (; p + 4 <= end; p += 4) {
        unsigned s0 = (unsigned)col[p],     s1 = (unsigned)col[p + 1];
        unsigned s2 = (unsigned)col[p + 2], s3 = (unsigned)col[p + 3];
        float w0 = __expf(lrelu(as2[s0] + adi));
        float w1 = __expf(lrelu(as2[s1] + adi));
        float w2 = __expf(lrelu(as2[s2] + adi));
        float w3 = __expf(lrelu(as2[s3] + adi));
        float2 v0 = h2v[s0];
        float2 v1 = h2v[s1];
        float2 v2 = h2v[s2];
        float2 v3 = h2v[s3];
        l += (w0 + w1) + (w2 + w3);
        a0 += (w0 * v0.x + w1 * v1.x) + (w2 * v2.x + w3 * v3.x);
        a1 += (w0 * v0.y + w1 * v1.y) + (w2 * v2.y + w3 * v3.y);
    }
    for (; p < end; ++p) {
        unsigned s = (unsigned)col[p];
        float w = __expf(lrelu(as2[s] + adi));
        float2 hv = h2v[s];
        l += w;
        a0 += w * hv.x;
        a1 += w * hv.y;
    }
    float inv = 1.0f / l;
    out[node * 2 + 0] = a0 * inv + b2[0];
    out[node * 2 + 1] = a1 * inv + b2[1];
}

// ---------------- launch ----------------
static inline char* ws_bump(char*& p, size_t bytes) {
    char* r = p;
    p += (bytes + 255) & ~(size_t)255;
    return r;
}

extern "C" void kernel_launch(void* const* d_in, const int* in_sizes, int n_in,
                              void* d_out, int out_size, void* d_ws, size_t ws_size,
                              hipStream_t stream) {
    const float* x   = (const float*)d_in[0];
    const int*   ei  = (const int*)d_in[1];
    const float* W1  = (const float*)d_in[2];
    const float* a1s = (const float*)d_in[3];
    const float* a1d = (const float*)d_in[4];
    const float* b1  = (const float*)d_in[5];
    const float* W2  = (const float*)d_in[6];
    const float* a2s = (const float*)d_in[7];
    const float* a2d = (const float*)d_in[8];
    const float* b2  = (const float*)d_in[9];
    float* out = (float*)d_out;

    const int E = in_sizes[1] / 2;
    const int* src = ei;        // edge_index[0]
    const int* dstp = ei + E;   // edge_index[1]

    char* p = (char*)d_ws;
    unsigned short* hb = (unsigned short*)ws_bump(p, (size_t)N_NODES * H_DIM * 2);   // 25.6 MB
    unsigned* tmp  = (unsigned*)ws_bump(p, (size_t)NBUCK * BKT_CAP * 4);             // 12.8 MB
    unsigned short* Wb = (unsigned short*)ws_bump(p, (size_t)IN_DIM * H_DIM * 2);    // 64 KB
    float* as1    = (float*)ws_bump(p, (size_t)N_NODES * 4);
    float* ad1    = (float*)ws_bump(p, (size_t)N_NODES * 4);
    int*   rowptr = (int*)  ws_bump(p, (size_t)(N_NODES + 1) * 4);
    int*   col    = (int*)  ws_bump(p, (size_t)E * 4);
    int*   bktAlloc = (int*)ws_bump(p, 1024 * 4);
    float* h2     = (float*)ws_bump(p, (size_t)N_NODES * 2 * 4);
    float* as2    = (float*)ws_bump(p, (size_t)N_NODES * 4);
    float* ad2    = (float*)ws_bump(p, (size_t)N_NODES * 4);

    const int nodeBlocks = (N_NODES + 255) / 256;                 // 391
    const int p1Blocks = (E + 512 * P1_EPT - 1) / (512 * P1_EPT); // 196
    const int gemmBlocks = (N_NODES + 127) / 128;                 // 782

    hipMemsetAsync(bktAlloc, 0, 1024 * 4, stream);
    prep_w<<<32, 256, 0, stream>>>(W1, Wb);

    fused_gemm_bin1<<<p1Blocks + gemmBlocks, 512, 0, stream>>>(
        x, Wb, a1s, a1d, hb, as1, ad1, src, dstp, bktAlloc, tmp, E, p1Blocks);
    bin_pass2<<<NBUCK, 1024, 0, stream>>>(tmp, bktAlloc, rowptr, col);

    agg1_kernel<<<(N_NODES + 3) / 4, 256, 0, stream>>>((const unsigned int*)hb, as1, ad1,
                                                       rowptr, col, b1, W2, a2s, a2d,
                                                       h2, as2, ad2);
    agg2_kernel<<<nodeBlocks, 256, 0, stream>>>(h2, as2, ad2, rowptr, col, b2, out);
}

// Round 14
// 151.454 us; speedup vs baseline: 1.2806x; 1.0329x over previous
//
#include <hip/hip_runtime.h>
#include <hip/hip_bf16.h>

#define N_NODES 100000
#define IN_DIM 256
#define H_DIM 128
#define NEG_SLOPE 0.2f

#define NBUCK 782            // ceil(100000/128) buckets of 128 nodes
#define BKT_CAP 4096         // per-bucket capacity (mean 2046, sigma ~45)
#define P1_EPT 16            // edges per thread in bin1 path (512 thr -> 8192 edges/block)

__device__ __forceinline__ float lrelu(float v) { return v > 0.f ? v : NEG_SLOPE * v; }
__device__ __forceinline__ float bflo(unsigned u) { return __uint_as_float(u << 16); }
__device__ __forceinline__ float bfhi(unsigned u) { return __uint_as_float(u & 0xffff0000u); }
__device__ __forceinline__ unsigned short f2bf(float f) {
    unsigned u = __float_as_uint(f);
    return (unsigned short)((u + 0x7fffu + ((u >> 16) & 1u)) >> 16);
}
__device__ __forceinline__ float rdlanef(float v, int j) {
    return __uint_as_float(__builtin_amdgcn_readlane(__float_as_uint(v), j));
}

typedef short bfrag __attribute__((ext_vector_type(8)));   // 8 bf16 (4 VGPRs)
typedef float f32x4 __attribute__((ext_vector_type(4)));

// ==== fused kernel (R8 known-good GEMM form): blocks [0,p1B) bin edges into
// ==== 128-node buckets; blocks [p1B,..) do MFMA GEMM h=bf16(x@W1) + as1/ad1 dots.
__global__ __launch_bounds__(512) void fused_gemm_bin1(const float* __restrict__ x,
                                                       const float* __restrict__ W,
                                                       const float* __restrict__ a_src,
                                                       const float* __restrict__ a_dst,
                                                       unsigned short* __restrict__ hb,
                                                       float* __restrict__ as1,
                                                       float* __restrict__ ad1,
                                                       const int* __restrict__ src,
                                                       const int* __restrict__ dst,
                                                       int* __restrict__ bktAlloc,
                                                       unsigned* __restrict__ tmp,
                                                       int E, int p1B) {
    __shared__ __align__(16) char smemraw[65536];
    const int tid = threadIdx.x;

    if ((int)blockIdx.x < p1B) {
        // ---------- bin1: partition packed (dl<<17|src) into 128-node buckets ----------
        int* hist  = (int*)smemraw;          // 1024 (>= NBUCK)
        int* basev = hist + 1024;
        int* hist2 = basev + 1024;           // 3*4KB = 12KB
        hist[tid] = 0; hist[tid + 512] = 0;
        hist2[tid] = 0; hist2[tid + 512] = 0;
        __syncthreads();
        const int e0 = blockIdx.x * (512 * P1_EPT) + tid * P1_EPT;
        int sv[P1_EPT], dv[P1_EPT];
#pragma unroll
        for (int i = 0; i < P1_EPT; ++i) {
            int e = e0 + i;
            if (e < E) { sv[i] = src[e]; dv[i] = dst[e]; }
            else dv[i] = -1;
        }
#pragma unroll
        for (int i = 0; i < P1_EPT; ++i)
            if (dv[i] >= 0) atomicAdd(&hist[dv[i] >> 7], 1);
        __syncthreads();
        for (int t = tid; t < NBUCK; t += 512) {
            int c = hist[t];
            basev[t] = c ? atomicAdd(&bktAlloc[t], c) : 0;
        }
        __syncthreads();
#pragma unroll
        for (int i = 0; i < P1_EPT; ++i) {
            if (dv[i] >= 0) {
                int b = dv[i] >> 7;
                int r = atomicAdd(&hist2[b], 1);
                int pos = basev[b] + r;
                if (pos < BKT_CAP)
                    tmp[b * BKT_CAP + pos] =
                        ((unsigned)(dv[i] & 127) << 17) | (unsigned)sv[i];
            }
        }
        return;
    }

    // ---------- GEMM path: 128 rows/block, in-kernel W staging (R8 form) ----------
    unsigned short* lds = (unsigned short*)smemraw;   // 64 KB: W bf16 swizzled, then D bounce
    const int w = tid >> 6;          // wave 0..7
    const int lane = tid & 63;
    const int lo = lane & 15;
    const int hi = lane >> 4;        // 0..3
    const int row0 = ((int)blockIdx.x - p1B) * 128;

    // stage W -> LDS, col-major [col][k] bf16, 8-k blocks XOR-swizzled by col&7
    {
        int col = tid & 127;
        int kb = tid >> 7;           // 0..3
        int c7 = col & 7;
#pragma unroll
        for (int i = 0; i < 16; ++i) {
            int k0 = i * 16 + kb * 4;
            float w0 = W[(k0 + 0) * H_DIM + col];
            float w1 = W[(k0 + 1) * H_DIM + col];
            float w2 = W[(k0 + 2) * H_DIM + col];
            float w3 = W[(k0 + 3) * H_DIM + col];
            int kblk = k0 >> 3;
            int rem = k0 & 7;
            unsigned short* d = &lds[col * 256 + ((kblk ^ c7) << 3) + rem];
            d[0] = f2bf(w0); d[1] = f2bf(w1); d[2] = f2bf(w2); d[3] = f2bf(w3);
        }
    }
    __syncthreads();

    int arow = row0 + w * 16 + lo;
    if (arow >= N_NODES) arow = N_NODES - 1;
    const float* xrow = x + (size_t)arow * IN_DIM + hi * 8;

    f32x4 acc[8] = {};
#pragma unroll
    for (int kc = 0; kc < 8; ++kc) {
        float4 xa = *reinterpret_cast<const float4*>(xrow + kc * 32);
        float4 xb = *reinterpret_cast<const float4*>(xrow + kc * 32 + 4);
        bfrag a;
        a[0] = (short)f2bf(xa.x); a[1] = (short)f2bf(xa.y);
        a[2] = (short)f2bf(xa.z); a[3] = (short)f2bf(xa.w);
        a[4] = (short)f2bf(xb.x); a[5] = (short)f2bf(xb.y);
        a[6] = (short)f2bf(xb.z); a[7] = (short)f2bf(xb.w);
        int kblk = kc * 4 + hi;
#pragma unroll
        for (int c = 0; c < 8; ++c) {
            int col = c * 16 + lo;
            const bfrag b = *reinterpret_cast<const bfrag*>(
                &lds[col * 256 + ((kblk ^ (col & 7)) << 3)]);
            acc[c] = __builtin_amdgcn_mfma_f32_16x16x32_bf16(a, b, acc[c], 0, 0, 0);
        }
    }

    // fused attention dots (fp32-exact)
    float asv[8], adv[8];
#pragma unroll
    for (int c = 0; c < 8; ++c) { asv[c] = a_src[c * 16 + lo]; adv[c] = a_dst[c * 16 + lo]; }
#pragma unroll
    for (int q = 0; q < 4; ++q) {
        float ps = 0.f, pd = 0.f;
#pragma unroll
        for (int c = 0; c < 8; ++c) { ps += acc[c][q] * asv[c]; pd += acc[c][q] * adv[c]; }
#pragma unroll
        for (int off = 8; off; off >>= 1) {
            ps += __shfl_xor(ps, off);
            pd += __shfl_xor(pd, off);
        }
        int grow = row0 + w * 16 + hi * 4 + q;
        if (lo == 0 && grow < N_NODES) { as1[grow] = ps; ad1[grow] = pd; }
    }

    // bounce D through LDS for coalesced bf16 stores
    __syncthreads();
#pragma unroll
    for (int c = 0; c < 8; ++c)
#pragma unroll
        for (int q = 0; q < 4; ++q)
            lds[(w * 16 + hi * 4 + q) * 128 + c * 16 + lo] = f2bf(acc[c][q]);
    __syncthreads();
#pragma unroll
    for (int i = 0; i < 4; ++i) {
        int idx = i * 512 + tid;
        int row = idx >> 4;
        int chunk = idx & 15;
        int grow = row0 + row;
        if (grow < N_NODES) {
            uint4 v = *reinterpret_cast<const uint4*>(&lds[row * 128 + chunk * 8]);
            *reinterpret_cast<uint4*>(&hb[(size_t)grow * H_DIM + chunk * 8]) = v;
        }
    }
}

// ---- bin2 (trimmed): per-bucket hist + 128-scan + scatter into BUCKET-STRIDED colG.
// ---- No global scan. nodeInfo = (bucket-local rp << 8) | deg.
__global__ __launch_bounds__(512) void bin_pass2(const unsigned* __restrict__ tmp,
                                                 const int* __restrict__ bktAlloc,
                                                 unsigned* __restrict__ colG,
                                                 unsigned* __restrict__ nodeInfo) {
    __shared__ int cnt[128], sc[128], rp[128];
    const int b = blockIdx.x;
    const int nb0 = b << 7;
    const int nmax = min(128, N_NODES - nb0);
    const int tid = threadIdx.x;
    const int myCnt = min(bktAlloc[b], BKT_CAP);
    const unsigned* btmp = tmp + (size_t)b * BKT_CAP;
    unsigned* bcol = colG + (size_t)b * BKT_CAP;

    if (tid < 128) cnt[tid] = 0;
    __syncthreads();
    for (int i = tid; i < myCnt; i += 512)
        atomicAdd(&cnt[btmp[i] >> 17], 1);
    __syncthreads();
    if (tid < 128) sc[tid] = cnt[tid];
    __syncthreads();
    for (int off = 1; off < 128; off <<= 1) {
        int u = (tid < 128 && tid >= off) ? sc[tid - off] : 0;
        __syncthreads();
        if (tid < 128) sc[tid] += u;
        __syncthreads();
    }
    if (tid < 128) { rp[tid] = sc[tid] - cnt[tid]; cnt[tid] = 0; }
    __syncthreads();
    if (tid < nmax)
        nodeInfo[nb0 + tid] = ((unsigned)rp[tid] << 8);   // deg filled below via cnt
    for (int i = tid; i < myCnt; i += 512) {
        unsigned e = btmp[i];
        int dl = (int)(e >> 17);
        int o = atomicAdd(&cnt[dl], 1);
        bcol[rp[dl] + o] = e & 0x1FFFFu;
    }
    __syncthreads();
    if (tid < nmax)
        nodeInfo[nb0 + tid] = ((unsigned)rp[tid] << 8) | (unsigned)cnt[tid];
}

// ------- Layer-1 aggregate (R8 known-good loop): wave per node, nodeInfo/colG -------
__global__ __launch_bounds__(256) void agg1_kernel(const unsigned int* __restrict__ hbu,
                                                   const float* __restrict__ as1,
                                                   const float* __restrict__ ad1,
                                                   const unsigned* __restrict__ colG,
                                                   const unsigned* __restrict__ nodeInfo,
                                                   const float* __restrict__ b1,
                                                   const float* __restrict__ W2,
                                                   const float* __restrict__ a2s,
                                                   const float* __restrict__ a2d,
                                                   float* __restrict__ h2,
                                                   float* __restrict__ as2,
                                                   float* __restrict__ ad2) {
    int node = blockIdx.x * 4 + (threadIdx.x >> 6);
    int lane = threadIdx.x & 63;
    if (node >= N_NODES) return;

    unsigned info = nodeInfo[node];
    const unsigned* ecol = colG + ((size_t)(node >> 7) * BKT_CAP + (info >> 8));
    const int deg = (int)(info & 255u);

    float adi = ad1[node];
    float wself = __expf(lrelu(as1[node] + adi));     // self loop weight
    unsigned hvs = hbu[(unsigned)node * 64u + lane];
    float ax = wself * bflo(hvs), ay = wself * bfhi(hvs);
    float lsum = 0.0f;

    for (int p0 = 0; p0 < deg; p0 += 64) {
        const int jn = min(64, deg - p0);
        int s_l = (int)ecol[p0 + (lane < jn ? lane : 0)];  // coalesced chunk read
        float e_l = (lane < jn) ? __expf(lrelu(as1[s_l] + adi)) : 0.0f;
        lsum += e_l;
        int j = 0;
        for (; j + 8 <= jn; j += 8) {
            const unsigned* r0 = hbu + ((size_t)__builtin_amdgcn_readlane(s_l, j)     << 6);
            const unsigned* r1 = hbu + ((size_t)__builtin_amdgcn_readlane(s_l, j + 1) << 6);
            const unsigned* r2 = hbu + ((size_t)__builtin_amdgcn_readlane(s_l, j + 2) << 6);
            const unsigned* r3 = hbu + ((size_t)__builtin_amdgcn_readlane(s_l, j + 3) << 6);
            const unsigned* r4 = hbu + ((size_t)__builtin_amdgcn_readlane(s_l, j + 4) << 6);
            const unsigned* r5 = hbu + ((size_t)__builtin_amdgcn_readlane(s_l, j + 5) << 6);
            const unsigned* r6 = hbu + ((size_t)__builtin_amdgcn_readlane(s_l, j + 6) << 6);
            const unsigned* r7 = hbu + ((size_t)__builtin_amdgcn_readlane(s_l, j + 7) << 6);
            unsigned v0 = r0[lane];
            unsigned v1 = r1[lane];
            unsigned v2 = r2[lane];
            unsigned v3 = r3[lane];
            unsigned v4 = r4[lane];
            unsigned v5 = r5[lane];
            unsigned v6 = r6[lane];
            unsigned v7 = r7[lane];
            float w0 = rdlanef(e_l, j);
            float w1 = rdlanef(e_l, j + 1);
            float w2 = rdlanef(e_l, j + 2);
            float w3 = rdlanef(e_l, j + 3);
            float w4 = rdlanef(e_l, j + 4);
            float w5 = rdlanef(e_l, j + 5);
            float w6 = rdlanef(e_l, j + 6);
            float w7 = rdlanef(e_l, j + 7);
            ax += (w0 * bflo(v0) + w1 * bflo(v1)) + (w2 * bflo(v2) + w3 * bflo(v3))
                + (w4 * bflo(v4) + w5 * bflo(v5)) + (w6 * bflo(v6) + w7 * bflo(v7));
            ay += (w0 * bfhi(v0) + w1 * bfhi(v1)) + (w2 * bfhi(v2) + w3 * bfhi(v3))
                + (w4 * bfhi(v4) + w5 * bfhi(v5)) + (w6 * bfhi(v6) + w7 * bfhi(v7));
        }
        for (; j < jn; ++j) {
            const unsigned* r = hbu + ((size_t)__builtin_amdgcn_readlane(s_l, j) << 6);
            float w = rdlanef(e_l, j);
            unsigned v = r[lane];
            ax += w * bflo(v);
            ay += w * bfhi(v);
        }
    }
#pragma unroll
    for (int off = 32; off; off >>= 1) lsum += __shfl_xor(lsum, off);
    float inv = 1.0f / (lsum + wself);

    float2 bb = *reinterpret_cast<const float2*>(&b1[lane * 2]);
    float o0 = fmaxf(ax * inv + bb.x, 0.0f);
    float o1 = fmaxf(ay * inv + bb.y, 0.0f);

    float4 w2 = *reinterpret_cast<const float4*>(&W2[lane * 4]);
    float p0 = o0 * w2.x + o1 * w2.z;
    float p1 = o0 * w2.y + o1 * w2.w;
#pragma unroll
    for (int off = 32; off; off >>= 1) {
        p0 += __shfl_xor(p0, off);
        p1 += __shfl_xor(p1, off);
    }
    if (lane == 0) {
        h2[node * 2 + 0] = p0;
        h2[node * 2 + 1] = p1;
        as2[node] = p0 * a2s[0] + p1 * a2s[1];
        ad2[node] = p0 * a2d[0] + p1 * a2d[1];
    }
}

// ---------------- Layer-2 aggregate: thread per node, no-max softmax ----------------
__global__ __launch_bounds__(256) void agg2_kernel(const float* __restrict__ h2,
                                                   const float* __restrict__ as2,
                                                   const float* __restrict__ ad2,
                                                   const unsigned* __restrict__ colG,
                                                   const unsigned* __restrict__ nodeInfo,
                                                   const float* __restrict__ b2,
                                                   float* __restrict__ out) {
    int node = blockIdx.x * 256 + threadIdx.x;
    if (node >= N_NODES) return;
    const float2* __restrict__ h2v = (const float2*)h2;
    unsigned info = nodeInfo[node];
    const unsigned* cp = colG + ((size_t)(node >> 7) * BKT_CAP + (info >> 8));
    const int deg = (int)(info & 255u);
    float adi = ad2[node];
    float w0s = __expf(lrelu(as2[node] + adi));
    float l = w0s;
    float2 hv0 = h2v[(unsigned)node];
    float a0 = w0s * hv0.x, a1 = w0s * hv0.y;
    int p = 0;
    for (; p + 4 <= deg; p += 4) {
        unsigned s0 = cp[p], s1 = cp[p + 1], s2 = cp[p + 2], s3 = cp[p + 3];
        float w0 = __expf(lrelu(as2[s0] + adi));
        float w1 = __expf(lrelu(as2[s1] + adi));
        float w2 = __expf(lrelu(as2[s2] + adi));
        float w3 = __expf(lrelu(as2[s3] + adi));
        float2 v0 = h2v[s0];
        float2 v1 = h2v[s1];
        float2 v2 = h2v[s2];
        float2 v3 = h2v[s3];
        l += (w0 + w1) + (w2 + w3);
        a0 += (w0 * v0.x + w1 * v1.x) + (w2 * v2.x + w3 * v3.x);
        a1 += (w0 * v0.y + w1 * v1.y) + (w2 * v2.y + w3 * v3.y);
    }
    for (; p < deg; ++p) {
        unsigned s = cp[p];
        float w = __expf(lrelu(as2[s] + adi));
        float2 hv = h2v[s];
        l += w;
        a0 += w * hv.x;
        a1 += w * hv.y;
    }
    float inv = 1.0f / l;
    out[node * 2 + 0] = a0 * inv + b2[0];
    out[node * 2 + 1] = a1 * inv + b2[1];
}

// ---------------- launch ----------------
static inline char* ws_bump(char*& p, size_t bytes) {
    char* r = p;
    p += (bytes + 255) & ~(size_t)255;
    return r;
}

extern "C" void kernel_launch(void* const* d_in, const int* in_sizes, int n_in,
                              void* d_out, int out_size, void* d_ws, size_t ws_size,
                              hipStream_t stream) {
    const float* x   = (const float*)d_in[0];
    const int*   ei  = (const int*)d_in[1];
    const float* W1  = (const float*)d_in[2];
    const float* a1s = (const float*)d_in[3];
    const float* a1d = (const float*)d_in[4];
    const float* b1  = (const float*)d_in[5];
    const float* W2  = (const float*)d_in[6];
    const float* a2s = (const float*)d_in[7];
    const float* a2d = (const float*)d_in[8];
    const float* b2  = (const float*)d_in[9];
    float* out = (float*)d_out;

    const int E = in_sizes[1] / 2;
    const int* src = ei;        // edge_index[0]
    const int* dstp = ei + E;   // edge_index[1]

    char* p = (char*)d_ws;
    unsigned short* hb = (unsigned short*)ws_bump(p, (size_t)N_NODES * H_DIM * 2);   // 25.6 MB
    unsigned* tmp  = (unsigned*)ws_bump(p, (size_t)NBUCK * BKT_CAP * 4);             // 12.8 MB
    unsigned* colG = (unsigned*)ws_bump(p, (size_t)NBUCK * BKT_CAP * 4);             // 12.8 MB
    unsigned* nodeInfo = (unsigned*)ws_bump(p, (size_t)N_NODES * 4);
    float* as1    = (float*)ws_bump(p, (size_t)N_NODES * 4);
    float* ad1    = (float*)ws_bump(p, (size_t)N_NODES * 4);
    int*   bktAlloc = (int*)ws_bump(p, 1024 * 4);
    float* h2     = (float*)ws_bump(p, (size_t)N_NODES * 2 * 4);
    float* as2    = (float*)ws_bump(p, (size_t)N_NODES * 4);
    float* ad2    = (float*)ws_bump(p, (size_t)N_NODES * 4);

    const int nodeBlocks = (N_NODES + 255) / 256;                 // 391
    const int p1Blocks = (E + 512 * P1_EPT - 1) / (512 * P1_EPT); // 196
    const int gemmBlocks = (N_NODES + 127) / 128;                 // 782

    hipMemsetAsync(bktAlloc, 0, 1024 * 4, stream);

    fused_gemm_bin1<<<p1Blocks + gemmBlocks, 512, 0, stream>>>(
        x, W1, a1s, a1d, hb, as1, ad1, src, dstp, bktAlloc, tmp, E, p1Blocks);
    bin_pass2<<<NBUCK, 512, 0, stream>>>(tmp, bktAlloc, colG, nodeInfo);

    agg1_kernel<<<(N_NODES + 3) / 4, 256, 0, stream>>>((const unsigned int*)hb, as1, ad1,
                                                       colG, nodeInfo, b1, W2, a2s, a2d,
                                                       h2, as2, ad2);
    agg2_kernel<<<nodeBlocks, 256, 0, stream>>>(h2, as2, ad2, colG, nodeInfo, b2, out);
}